// Round 1
// baseline (789.617 us; speedup 1.0000x reference)
//
#include <hip/hip_runtime.h>
#include <math.h>

// DCNv2 fused: offset/mask conv + bilinear gather + modulated GEMM + bias.
// Shapes: x[8,64,64,256] f32, omw[3,3,256,27], omb[27], wmat[2304,256], bias[256]
// out[8,64,64,256] f32.

#define BB   8
#define HH   64
#define WW   64
#define CIN  256
#define FF   256
#define KPTS 9
#define OCH  27      // 18 offsets + 9 masks
#define MTILE 32     // pixels per block
#define CHUNK 64     // channels per K-chunk
#define NCHUNK (CIN / CHUNK)   // 4

__global__ __launch_bounds__(256) void dcn_fused(
    const float* __restrict__ x,     // [B,H,W,C]
    const float* __restrict__ omw,   // [3,3,C,27] (HWIO)
    const float* __restrict__ omb,   // [27]
    const float* __restrict__ wmat,  // [9*C, F]
    const float* __restrict__ bias,  // [F]
    float* __restrict__ out)         // [B,H,W,F]
{
    __shared__ float A[CHUNK][MTILE + 1];  // [cc][m], pad -> stride 33 (odd, conflict-free)
    __shared__ float om_s[MTILE][28];      // om results per pixel
    __shared__ float cw[MTILE][4];         // bilinear corner weights (mask-premultiplied)
    __shared__ int   ca[MTILE][4];         // corner base addresses (elements, clamped)

    const int tid   = threadIdx.x;
    const int pbase = blockIdx.x * MTILE;

    // staging map: each thread stages column cc for 8 m-rows
    const int ccid = tid & 63;     // 0..63
    const int mg2  = tid >> 6;     // 0..3 -> m = mg2*8 + i

    // ---------------- Phase 1: offset/mask conv (im2col GEMM, N=27) ----------------
    const int och = tid & 31;      // 0..31 (27 active)
    const int mg1 = tid >> 5;      // 0..7 -> m = mg1*4 + i
    float acc1[4] = {0.f, 0.f, 0.f, 0.f};

    for (int kk = 0; kk < KPTS; ++kk) {
        const int ky = kk / 3, kx = kk % 3;
        for (int ch = 0; ch < NCHUNK; ++ch) {
            const int cbase = ch * CHUNK;
            __syncthreads();
            // stage undeformed patch column
            #pragma unroll
            for (int i = 0; i < 8; ++i) {
                const int m = mg2 * 8 + i;
                const int p = pbase + m;
                const int b = p >> 12, oh = (p >> 6) & 63, ow = p & 63;
                const int iy = oh - 1 + ky, ix = ow - 1 + kx;
                float v = 0.f;
                if (iy >= 0 && iy < HH && ix >= 0 && ix < WW)
                    v = x[((b * HH + iy) * WW + ix) * CIN + cbase + ccid];
                A[ccid][m] = v;
            }
            __syncthreads();
            if (och < OCH) {
                for (int cc = 0; cc < CHUNK; ++cc) {
                    const float bv = omw[((kk * CIN) + cbase + cc) * OCH + och];
                    #pragma unroll
                    for (int i = 0; i < 4; ++i)
                        acc1[i] += A[cc][mg1 * 4 + i] * bv;
                }
            }
        }
    }
    __syncthreads();
    if (och < OCH) {
        const float ob = omb[och];
        #pragma unroll
        for (int i = 0; i < 4; ++i)
            om_s[mg1 * 4 + i][och] = acc1[i] + ob;
    }
    __syncthreads();

    // ---------------- Phase 2: deformable GEMM (N=256) ----------------
    const int f4  = (tid & 63) * 4;  // f = f4..f4+3
    const int mgc = tid >> 6;        // m = mgc*8 + j
    float acc[8][4];
    #pragma unroll
    for (int j = 0; j < 8; ++j)
        #pragma unroll
        for (int i = 0; i < 4; ++i) acc[j][i] = 0.f;

    for (int kk = 0; kk < KPTS; ++kk) {
        // compute bilinear params for this kk (one thread per pixel)
        if (tid < MTILE) {
            const int m = tid;
            const int p = pbase + m;
            const int b = p >> 12, oh = (p >> 6) & 63, ow = p & 63;
            const int ky = kk / 3, kx = kk % 3;
            const float dy = om_s[m][2 * kk];
            const float dx = om_s[m][2 * kk + 1];
            const float mask = 2.f / (1.f + __expf(-om_s[m][18 + kk]));
            const float py = (float)(oh - 1 + ky) + dy;
            const float px = (float)(ow - 1 + kx) + dx;
            const float y0f = floorf(py), x0f = floorf(px);
            const float wy1 = py - y0f, wx1 = px - x0f;
            const float wy0 = 1.f - wy1, wx0 = 1.f - wx1;
            const int y0 = (int)y0f, x0 = (int)x0f;
            const int y1 = y0 + 1, x1 = x0 + 1;
            const bool vy0 = (y0 >= 0) && (y0 < HH);
            const bool vy1 = (y1 >= 0) && (y1 < HH);
            const bool vx0 = (x0 >= 0) && (x0 < WW);
            const bool vx1 = (x1 >= 0) && (x1 < WW);
            const int y0c = min(max(y0, 0), HH - 1), y1c = min(max(y1, 0), HH - 1);
            const int x0c = min(max(x0, 0), WW - 1), x1c = min(max(x1, 0), WW - 1);
            const int rb = b * HH;
            ca[m][0] = ((rb + y0c) * WW + x0c) * CIN;
            ca[m][1] = ((rb + y0c) * WW + x1c) * CIN;
            ca[m][2] = ((rb + y1c) * WW + x0c) * CIN;
            ca[m][3] = ((rb + y1c) * WW + x1c) * CIN;
            cw[m][0] = (vy0 && vx0) ? mask * wy0 * wx0 : 0.f;
            cw[m][1] = (vy0 && vx1) ? mask * wy0 * wx1 : 0.f;
            cw[m][2] = (vy1 && vx0) ? mask * wy1 * wx0 : 0.f;
            cw[m][3] = (vy1 && vx1) ? mask * wy1 * wx1 : 0.f;
        }
        for (int ch = 0; ch < NCHUNK; ++ch) {
            const int cbase = ch * CHUNK;
            __syncthreads();   // params visible; previous compute done before A overwrite
            // stage deformed, modulated patch column (4-corner bilinear)
            #pragma unroll
            for (int i = 0; i < 8; ++i) {
                const int m = mg2 * 8 + i;
                const int cidx = cbase + ccid;
                const float v = cw[m][0] * x[ca[m][0] + cidx]
                              + cw[m][1] * x[ca[m][1] + cidx]
                              + cw[m][2] * x[ca[m][2] + cidx]
                              + cw[m][3] * x[ca[m][3] + cidx];
                A[ccid][m] = v;
            }
            __syncthreads();
            const float* brow = wmat + (size_t)(kk * CIN + cbase) * FF + f4;
            for (int cc = 0; cc < CHUNK; ++cc) {
                const float4 bv = *(const float4*)(brow + cc * FF);
                #pragma unroll
                for (int j = 0; j < 8; ++j) {
                    const float a = A[cc][mgc * 8 + j];
                    acc[j][0] += a * bv.x;
                    acc[j][1] += a * bv.y;
                    acc[j][2] += a * bv.z;
                    acc[j][3] += a * bv.w;
                }
            }
        }
    }

    // ---------------- Epilogue: + bias, store ----------------
    const float4 bb = *(const float4*)(bias + f4);
    #pragma unroll
    for (int j = 0; j < 8; ++j) {
        const int m = mgc * 8 + j;
        const int p = pbase + m;
        float4 o;
        o.x = acc[j][0] + bb.x;
        o.y = acc[j][1] + bb.y;
        o.z = acc[j][2] + bb.z;
        o.w = acc[j][3] + bb.w;
        *(float4*)(out + (size_t)p * FF + f4) = o;
    }
}

extern "C" void kernel_launch(void* const* d_in, const int* in_sizes, int n_in,
                              void* d_out, int out_size, void* d_ws, size_t ws_size,
                              hipStream_t stream) {
    const float* x    = (const float*)d_in[0];
    const float* omw  = (const float*)d_in[1];
    const float* omb  = (const float*)d_in[2];
    const float* wmat = (const float*)d_in[3];
    const float* bias = (const float*)d_in[4];
    float* out = (float*)d_out;

    const int M = BB * HH * WW;          // 32768 pixels
    const int nblocks = M / MTILE;       // 1024
    dcn_fused<<<nblocks, 256, 0, stream>>>(x, omw, omb, wmat, bias, out);
}

// Round 2
// 298.525 us; speedup vs baseline: 2.6451x; 2.6451x over previous
//
#include <hip/hip_runtime.h>
#include <math.h>

// DCNv2 fused, f16-MFMA version.
// x[8,64,64,256] f32, omw[3,3,256,27], omb[27], wmat[2304,256], bias[256] -> out[8,64,64,256] f32

#define BB 8
#define HH 64
#define WW 64
#define CIN 256
#define FF 256
#define KPTS 9
#define OCH 27
#define MT 64            // pixels per block (one (b,oh) row: ow = m)
#define KSTEPS 72        // 2304 / 32
#define ASTRIDE 56       // f16 elems per A row: 32 + 24 pad -> 112B rows (16B aligned, 2-way banks)

typedef _Float16 half8  __attribute__((ext_vector_type(8)));
typedef _Float16 half4v __attribute__((ext_vector_type(4)));
typedef float    floatx4 __attribute__((ext_vector_type(4)));

// ---------------- pre-pass: f32 -> f16 swizzled weights ----------------
// wsB[(k/8)*256 + n][8] = wmat[k][n]
__global__ __launch_bounds__(256) void convert_wmat(const float* __restrict__ wmat,
                                                    _Float16* __restrict__ wsB) {
    const int k = blockIdx.x;          // 0..2303
    const int n = threadIdx.x;         // 0..255
    wsB[((size_t)(k >> 3) * FF + n) * 8 + (k & 7)] = (_Float16)wmat[k * FF + n];
}

// wsOM[(k/8)*32 + n][8] = omw[k][n] (n>=27 -> 0)
__global__ __launch_bounds__(256) void convert_omw(const float* __restrict__ omw,
                                                   _Float16* __restrict__ wsOM) {
    const int t = blockIdx.x * 256 + threadIdx.x;  // 288*256 = 2304*32
    const int k = t >> 5, n = t & 31;
    const float v = (n < OCH) ? omw[k * OCH + n] : 0.f;
    wsOM[((size_t)(k >> 3) * 32 + n) * 8 + (k & 7)] = (_Float16)v;
}

// ---------------- main fused kernel ----------------
__global__ __launch_bounds__(256) void dcn_mfma(
    const float* __restrict__ x,
    const float* __restrict__ omb,
    const _Float16* __restrict__ wsB,
    const _Float16* __restrict__ wsOM,
    const float* __restrict__ bias,
    float* __restrict__ out)
{
    __shared__ _Float16 Ah[MT * ASTRIDE];     // 7168 B
    __shared__ float    om_s[MT][28];         // 7168 B
    __shared__ floatx4  cwS[MT][KPTS];        // 9216 B  mask-premultiplied bilinear weights
    __shared__ int4     caS[MT][KPTS];        // 9216 B  clamped corner element bases

    const int tid  = threadIdx.x;
    const int w    = tid >> 6;      // wave 0..3
    const int lane = tid & 63;
    const int q    = lane >> 4;     // 0..3
    const int lr   = lane & 15;
    const int b    = blockIdx.x >> 6;
    const int oh   = blockIdx.x & 63;
    const int pbase = blockIdx.x * MT;

    // staging slots: (m, channel-group-of-4)
    const int m0s = tid >> 3;       // 0..31 (+32 for r=1)
    const int cg  = tid & 7;

    const half8* wsOM8 = (const half8*)wsOM;
    const half8* wsB8  = (const half8*)wsB;

    // ================= Phase 1: offset/mask conv via MFMA =================
    floatx4 acc1[2] = {{0.f,0.f,0.f,0.f},{0.f,0.f,0.f,0.f}};
    for (int s = 0; s < KSTEPS; ++s) {
        const int kk = s >> 3, cb = (s & 7) << 5;
        const int ky = kk / 3, kx = kk % 3;
        const int iy = oh - 1 + ky;
        __syncthreads();
        #pragma unroll
        for (int r = 0; r < 2; ++r) {
            const int m = m0s + r * 32;
            const int ix = m - 1 + kx;          // ow == m
            floatx4 v = {0.f, 0.f, 0.f, 0.f};
            if (iy >= 0 && iy < HH && ix >= 0 && ix < WW)
                v = *(const floatx4*)(x + (((b * HH + iy) * WW + ix) * CIN + cb + cg * 4));
            half4v hv;
            hv.x = (_Float16)v.x; hv.y = (_Float16)v.y;
            hv.z = (_Float16)v.z; hv.w = (_Float16)v.w;
            *(half4v*)(Ah + m * ASTRIDE + cg * 4) = hv;
        }
        __syncthreads();
        const half8 a = *(const half8*)(Ah + (w * 16 + lr) * ASTRIDE + q * 8);  // m-tile = wave
        const int kb = s * 4 + q;
        #pragma unroll
        for (int nt = 0; nt < 2; ++nt) {
            const half8 bf = wsOM8[kb * 32 + nt * 16 + lr];
            acc1[nt] = __builtin_amdgcn_mfma_f32_16x16x32_f16(a, bf, acc1[nt], 0, 0, 0);
        }
    }
    __syncthreads();
    #pragma unroll
    for (int nt = 0; nt < 2; ++nt) {
        const int och = nt * 16 + lr;
        if (och < OCH) {
            const float ob = omb[och];
            #pragma unroll
            for (int reg = 0; reg < 4; ++reg) {
                const int m = w * 16 + q * 4 + reg;   // C/D: row=(lane>>4)*4+reg
                om_s[m][och] = acc1[nt][reg] + ob;
            }
        }
    }
    __syncthreads();

    // ================= bilinear params (per pixel x kernel point) =================
    for (int i = tid; i < MT * KPTS; i += 256) {
        const int m = i / KPTS, kk = i % KPTS;
        const int ky = kk / 3, kx = kk % 3;
        const float dy = om_s[m][2 * kk];
        const float dx = om_s[m][2 * kk + 1];
        const float mask = 2.f / (1.f + __expf(-om_s[m][18 + kk]));
        const float py = (float)(oh - 1 + ky) + dy;
        const float px = (float)(m - 1 + kx) + dx;
        const float y0f = floorf(py), x0f = floorf(px);
        const float wy1 = py - y0f, wx1 = px - x0f;
        const float wy0 = 1.f - wy1, wx0 = 1.f - wx1;
        const int y0 = (int)y0f, x0 = (int)x0f;
        const int y1 = y0 + 1, x1 = x0 + 1;
        const bool vy0 = (y0 >= 0) && (y0 < HH);
        const bool vy1 = (y1 >= 0) && (y1 < HH);
        const bool vx0 = (x0 >= 0) && (x0 < WW);
        const bool vx1 = (x1 >= 0) && (x1 < WW);
        const int y0c = min(max(y0, 0), HH - 1), y1c = min(max(y1, 0), HH - 1);
        const int x0c = min(max(x0, 0), WW - 1), x1c = min(max(x1, 0), WW - 1);
        const int rb = b * HH;
        int4 ca;
        ca.x = ((rb + y0c) * WW + x0c) * CIN;
        ca.y = ((rb + y0c) * WW + x1c) * CIN;
        ca.z = ((rb + y1c) * WW + x0c) * CIN;
        ca.w = ((rb + y1c) * WW + x1c) * CIN;
        floatx4 cw;
        cw.x = (vy0 && vx0) ? mask * wy0 * wx0 : 0.f;
        cw.y = (vy0 && vx1) ? mask * wy0 * wx1 : 0.f;
        cw.z = (vy1 && vx0) ? mask * wy1 * wx0 : 0.f;
        cw.w = (vy1 && vx1) ? mask * wy1 * wx1 : 0.f;
        caS[m][kk] = ca;
        cwS[m][kk] = cw;
    }

    // ================= Phase 2: deformable GEMM via MFMA =================
    floatx4 acc[4][4];
    #pragma unroll
    for (int mt = 0; mt < 4; ++mt)
        #pragma unroll
        for (int nt = 0; nt < 4; ++nt)
            acc[mt][nt] = (floatx4){0.f, 0.f, 0.f, 0.f};

    const int n0w = w * 64;
    for (int s = 0; s < KSTEPS; ++s) {
        const int kk = s >> 3, cb = (s & 7) << 5;
        __syncthreads();
        #pragma unroll
        for (int r = 0; r < 2; ++r) {
            const int m = m0s + r * 32;
            const floatx4 cw = cwS[m][kk];
            const int4 ca = caS[m][kk];
            const int co = cb + cg * 4;
            const floatx4 c0 = *(const floatx4*)(x + ca.x + co);
            const floatx4 c1 = *(const floatx4*)(x + ca.y + co);
            const floatx4 c2 = *(const floatx4*)(x + ca.z + co);
            const floatx4 c3 = *(const floatx4*)(x + ca.w + co);
            const floatx4 v = cw.x * c0 + cw.y * c1 + cw.z * c2 + cw.w * c3;
            half4v hv;
            hv.x = (_Float16)v.x; hv.y = (_Float16)v.y;
            hv.z = (_Float16)v.z; hv.w = (_Float16)v.w;
            *(half4v*)(Ah + m * ASTRIDE + cg * 4) = hv;
        }
        __syncthreads();
        half8 afr[4];
        #pragma unroll
        for (int mt = 0; mt < 4; ++mt)
            afr[mt] = *(const half8*)(Ah + (mt * 16 + lr) * ASTRIDE + q * 8);
        const int kb = s * 4 + q;
        #pragma unroll
        for (int nt = 0; nt < 4; ++nt) {
            const half8 bf = wsB8[kb * FF + n0w + nt * 16 + lr];
            #pragma unroll
            for (int mt = 0; mt < 4; ++mt)
                acc[mt][nt] = __builtin_amdgcn_mfma_f32_16x16x32_f16(afr[mt], bf, acc[mt][nt], 0, 0, 0);
        }
    }

    // ================= epilogue =================
    #pragma unroll
    for (int nt = 0; nt < 4; ++nt) {
        const int f = n0w + nt * 16 + lr;
        const float bv = bias[f];
        #pragma unroll
        for (int mt = 0; mt < 4; ++mt)
            #pragma unroll
            for (int reg = 0; reg < 4; ++reg) {
                const int m = mt * 16 + q * 4 + reg;
                out[(size_t)(pbase + m) * FF + f] = acc[mt][nt][reg] + bv;
            }
    }
}

// ---------------- fp32 fallback (round-1 kernel), used only if ws too small ----------------
#define MTILE 32
#define CHUNK 64
#define NCHUNK (CIN / CHUNK)

__global__ __launch_bounds__(256) void dcn_fused(
    const float* __restrict__ x, const float* __restrict__ omw,
    const float* __restrict__ omb, const float* __restrict__ wmat,
    const float* __restrict__ bias, float* __restrict__ out)
{
    __shared__ float A[CHUNK][MTILE + 1];
    __shared__ float om_s[MTILE][28];
    __shared__ float cw[MTILE][4];
    __shared__ int   ca[MTILE][4];

    const int tid = threadIdx.x;
    const int pbase = blockIdx.x * MTILE;
    const int ccid = tid & 63;
    const int mg2 = tid >> 6;
    const int och = tid & 31;
    const int mg1 = tid >> 5;
    float acc1[4] = {0.f, 0.f, 0.f, 0.f};

    for (int kk = 0; kk < KPTS; ++kk) {
        const int ky = kk / 3, kx = kk % 3;
        for (int ch = 0; ch < NCHUNK; ++ch) {
            const int cbase = ch * CHUNK;
            __syncthreads();
            #pragma unroll
            for (int i = 0; i < 8; ++i) {
                const int m = mg2 * 8 + i;
                const int p = pbase + m;
                const int bb = p >> 12, oh = (p >> 6) & 63, ow = p & 63;
                const int iy = oh - 1 + ky, ix = ow - 1 + kx;
                float v = 0.f;
                if (iy >= 0 && iy < HH && ix >= 0 && ix < WW)
                    v = x[((bb * HH + iy) * WW + ix) * CIN + cbase + ccid];
                A[ccid][m] = v;
            }
            __syncthreads();
            if (och < OCH) {
                for (int cc = 0; cc < CHUNK; ++cc) {
                    const float bv = omw[((kk * CIN) + cbase + cc) * OCH + och];
                    #pragma unroll
                    for (int i = 0; i < 4; ++i)
                        acc1[i] += A[cc][mg1 * 4 + i] * bv;
                }
            }
        }
    }
    __syncthreads();
    if (och < OCH) {
        const float ob = omb[och];
        #pragma unroll
        for (int i = 0; i < 4; ++i)
            om_s[mg1 * 4 + i][och] = acc1[i] + ob;
    }
    __syncthreads();

    const int f4 = (tid & 63) * 4;
    const int mgc = tid >> 6;
    float acc[8][4];
    #pragma unroll
    for (int j = 0; j < 8; ++j)
        #pragma unroll
        for (int i = 0; i < 4; ++i) acc[j][i] = 0.f;

    for (int kk = 0; kk < KPTS; ++kk) {
        if (tid < MTILE) {
            const int m = tid;
            const int p = pbase + m;
            const int bb = p >> 12, oh = (p >> 6) & 63, ow = p & 63;
            const int ky = kk / 3, kx = kk % 3;
            const float dy = om_s[m][2 * kk];
            const float dx = om_s[m][2 * kk + 1];
            const float mask = 2.f / (1.f + __expf(-om_s[m][18 + kk]));
            const float py = (float)(oh - 1 + ky) + dy;
            const float px = (float)(ow - 1 + kx) + dx;
            const float y0f = floorf(py), x0f = floorf(px);
            const float wy1 = py - y0f, wx1 = px - x0f;
            const float wy0 = 1.f - wy1, wx0 = 1.f - wx1;
            const int y0 = (int)y0f, x0 = (int)x0f;
            const int y1 = y0 + 1, x1 = x0 + 1;
            const bool vy0 = (y0 >= 0) && (y0 < HH);
            const bool vy1 = (y1 >= 0) && (y1 < HH);
            const bool vx0 = (x0 >= 0) && (x0 < WW);
            const bool vx1 = (x1 >= 0) && (x1 < WW);
            const int y0c = min(max(y0, 0), HH - 1), y1c = min(max(y1, 0), HH - 1);
            const int x0c = min(max(x0, 0), WW - 1), x1c = min(max(x1, 0), WW - 1);
            const int rb = bb * HH;
            ca[m][0] = ((rb + y0c) * WW + x0c) * CIN;
            ca[m][1] = ((rb + y0c) * WW + x1c) * CIN;
            ca[m][2] = ((rb + y1c) * WW + x0c) * CIN;
            ca[m][3] = ((rb + y1c) * WW + x1c) * CIN;
            cw[m][0] = (vy0 && vx0) ? mask * wy0 * wx0 : 0.f;
            cw[m][1] = (vy0 && vx1) ? mask * wy0 * wx1 : 0.f;
            cw[m][2] = (vy1 && vx0) ? mask * wy1 * wx0 : 0.f;
            cw[m][3] = (vy1 && vx1) ? mask * wy1 * wx1 : 0.f;
        }
        for (int ch = 0; ch < NCHUNK; ++ch) {
            const int cbase = ch * CHUNK;
            __syncthreads();
            #pragma unroll
            for (int i = 0; i < 8; ++i) {
                const int m = mg2 * 8 + i;
                const int cidx = cbase + ccid;
                const float v = cw[m][0] * x[ca[m][0] + cidx]
                              + cw[m][1] * x[ca[m][1] + cidx]
                              + cw[m][2] * x[ca[m][2] + cidx]
                              + cw[m][3] * x[ca[m][3] + cidx];
                A[ccid][m] = v;
            }
            __syncthreads();
            const float* brow = wmat + (size_t)(kk * CIN + cbase) * FF + f4;
            for (int cc = 0; cc < CHUNK; ++cc) {
                const float4 bv = *(const float4*)(brow + cc * FF);
                #pragma unroll
                for (int j = 0; j < 8; ++j) {
                    const float a = A[cc][mgc * 8 + j];
                    acc[j][0] += a * bv.x;
                    acc[j][1] += a * bv.y;
                    acc[j][2] += a * bv.z;
                    acc[j][3] += a * bv.w;
                }
            }
        }
    }

    const float4 bb4 = *(const float4*)(bias + f4);
    #pragma unroll
    for (int j = 0; j < 8; ++j) {
        const int m = mgc * 8 + j;
        const int p = pbase + m;
        float4 o;
        o.x = acc[j][0] + bb4.x;
        o.y = acc[j][1] + bb4.y;
        o.z = acc[j][2] + bb4.z;
        o.w = acc[j][3] + bb4.w;
        *(float4*)(out + (size_t)p * FF + f4) = o;
    }
}

extern "C" void kernel_launch(void* const* d_in, const int* in_sizes, int n_in,
                              void* d_out, int out_size, void* d_ws, size_t ws_size,
                              hipStream_t stream) {
    const float* x    = (const float*)d_in[0];
    const float* omw  = (const float*)d_in[1];
    const float* omb  = (const float*)d_in[2];
    const float* wmat = (const float*)d_in[3];
    const float* bias = (const float*)d_in[4];
    float* out = (float*)d_out;

    const size_t needB  = (size_t)2304 * FF * sizeof(_Float16);   // 1,179,648 B
    const size_t needOM = (size_t)288 * 32 * 8 * sizeof(_Float16); // 147,456 B

    if (ws_size >= needB + needOM) {
        _Float16* wsB  = (_Float16*)d_ws;
        _Float16* wsOM = (_Float16*)((char*)d_ws + needB);
        convert_wmat<<<2304, 256, 0, stream>>>(wmat, wsB);
        convert_omw<<<288, 256, 0, stream>>>(omw, wsOM);
        dcn_mfma<<<BB * HH, 256, 0, stream>>>(x, omb, wsB, wsOM, bias, out);
    } else {
        const int nblocks = (BB * HH * WW) / MTILE;
        dcn_fused<<<nblocks, 256, 0, stream>>>(x, omw, omb, wmat, bias, out);
    }
}